// Round 11
// baseline (131.577 us; speedup 1.0000x reference)
//
#include <hip/hip_runtime.h>
#include <hip/hip_bf16.h>

#define B_ 128
#define S_ 513
#define H_ 256
#define SH_ (S_ * H_)

typedef __attribute__((ext_vector_type(8))) short short8;
typedef __attribute__((ext_vector_type(4))) float f32x4;

// Pack 8 fp32 -> 8 bf16 (RNE) via the HW packed converter.
static __device__ inline short8 pack8(float4 a, float4 b) {
    union { short8 s; __hip_bfloat162 h[4]; } u;
    u.h[0] = __float22bfloat162_rn(make_float2(a.x, a.y));
    u.h[1] = __float22bfloat162_rn(make_float2(a.z, a.w));
    u.h[2] = __float22bfloat162_rn(make_float2(b.x, b.y));
    u.h[3] = __float22bfloat162_rn(make_float2(b.z, b.w));
    return u.s;
}
static __device__ inline short8 pack8v(f32x4 a, f32x4 b) {
    union { short8 s; __hip_bfloat162 h[4]; } u;
    u.h[0] = __float22bfloat162_rn(make_float2(a[0], a[1]));
    u.h[1] = __float22bfloat162_rn(make_float2(a[2], a[3]));
    u.h[2] = __float22bfloat162_rn(make_float2(b[0], b[1]));
    u.h[3] = __float22bfloat162_rn(make_float2(b[2], b[3]));
    return u.s;
}

// Prep: W fp32 -> bf16 in fragment-major layout (m, kc, d, 8) so W fragment
// loads are coalesced (16 lanes -> 256 B run). Also bias sum (256 floats).
__global__ void prep_kernel(const float* __restrict__ W,
                            const float* __restrict__ bias,
                            unsigned short* __restrict__ Wbf,
                            float* __restrict__ bsum) {
    int t = blockIdx.x * 256 + threadIdx.x;
    if (t < 5 * 32 * 256) {                 // one thread per (m, d, kc)
        int m  = t >> 13;                   // t / 8192
        int r  = t & 8191;
        int d  = r >> 5;
        int kc = r & 31;                    // 8-elem k-chunk
        const float* src = W + (((size_t)m * 256 + d) * 256 + kc * 8);
        float4 v0 = *(const float4*)src;
        float4 v1 = *(const float4*)(src + 4);
        *(short8*)(Wbf + ((size_t)(m * 32 + kc) * 256 + d) * 8) = pack8(v0, v1);
    }
    if (t < H_) {
        float s = 0.f;
#pragma unroll
        for (int i = 0; i < 5; ++i) s += bias[i * H_ + t];
        bsum[t] = s;
    }
}

// R10 retry with the W-hoist FORCED. R10's VGPR_Count=56 proved the compiler
// sank the "hoisted" W loads back into the K-loop (rematerialization), so
// the chain-free-compute experiment never ran. This version pins each W
// fragment with a "+v" keep-alive asm (compiler must treat the reg as
// modified -> cannot re-load after the barrier) + sched_barrier(0) fence.
// Bias load moved to the epilogue to cut pre-barrier register pressure.
// Everything else identical to R10: 512 thr / 8 waves x 32-d slices,
// 32-row b-major tiles, gload_lds pre-swizzled-source staging, one
// __syncthreads, pure LDS+MFMA K-loop, 2 blocks/CU.
template <int MODE>
__global__ __launch_bounds__(512, 4)
void sel_gemm_kernel(const float* __restrict__ x,
                     const void* __restrict__ Wp,
                     const void* __restrict__ bp,
                     float* __restrict__ out) {
    __shared__ float As[32 * 256];          // 32 KB, gload_lds (linear dest)

    const int bid  = blockIdx.x;
    const int t    = threadIdx.x;
    const int lane = t & 63;
    const int w8   = t >> 6;        // 0..7 : d-slice (w8*32)
    const int lrow = lane & 15;
    const int quad = lane >> 4;

    int m_idx, rmax;
    size_t xrow0, rstride;
    if (bid < 2048) {
        const int b   = bid >> 4;
        const int sub = bid & 15;
        const int par = sub & 1;
        const int q   = sub >> 1;           // 0..7
        const int sbase = (par ? 3 : 4) + q * 64;
        m_idx   = par ? 3 : 4;
        xrow0   = (size_t)b * S_ + sbase;   // row r -> s = sbase + 2r
        rstride = 2;
        rmax    = (512 - sbase) >> 1;
        if (rmax > 31) rmax = 31;
    } else {
        const int e  = bid - 2048;          // 0..11
        const int s  = e >> 2;              // 0..2
        const int bq = e & 3;
        m_idx   = s;
        xrow0   = (size_t)(bq * 32) * S_ + s;   // row r -> b = bq*32+r
        rstride = S_;
        rmax    = 31;
    }

    // ---- 1) W-hoist: this wave's 32-d slice, all K=256 -> 16 short8
    // (64 VGPR). Issued FIRST so its L2 latency hides under the HBM stage.
    short8 wfr[2][8];
    if (MODE == 0) {
        const unsigned short* Wb = (const unsigned short*)Wp;
#pragma unroll
        for (int kk = 0; kk < 8; ++kk) {
            const unsigned short* Wk =
                Wb + ((size_t)(m_idx * 32 + kk * 4 + quad) * 256) * 8;
#pragma unroll
            for (int j = 0; j < 2; ++j)
                wfr[j][kk] = *(const short8*)(Wk +
                              (size_t)(w8 * 32 + j * 16 + lrow) * 8);
        }
    } else {
        const float* Wb = (const float*)Wp + (size_t)m_idx * H_ * H_;
#pragma unroll
        for (int kk = 0; kk < 8; ++kk)
#pragma unroll
            for (int j = 0; j < 2; ++j) {
                const float* wrow = Wb +
                    (size_t)(w8 * 32 + j * 16 + lrow) * H_ + kk * 32 + quad * 8;
                float4 v0 = *(const float4*)wrow;
                float4 v1 = *(const float4*)(wrow + 4);
                wfr[j][kk] = pack8(v0, v1);
            }
    }

    // ---- 2) Stage x: 32 rows x 256 fp32 via gload_lds, 4 rows/wave (one
    // instruction = one full 1 KB row, wave-uniform LDS base + lane*16).
    // Per-lane GLOBAL chunk = lane^(row&7) so LDS chunk c holds global
    // chunk c^(row&7); K-loop reads apply the same XOR (<=2-way, free).
#pragma unroll
    for (int it = 0; it < 4; ++it) {
        const int row = w8 * 4 + it;        // 0..31
        int rg = row <= rmax ? row : rmax;  // clamp data; slot stays row
        const float* src = x + (xrow0 + rstride * rg) * H_
                             + ((lane ^ (row & 7)) << 2);
        __builtin_amdgcn_global_load_lds(
            (const __attribute__((address_space(1))) unsigned int*)src,
            (__attribute__((address_space(3))) unsigned int*)&As[row * 256],
            16, 0, 0);
    }

    f32x4 acc[2][2];
#pragma unroll
    for (int i = 0; i < 2; ++i)
#pragma unroll
        for (int j = 0; j < 2; ++j) {
            f32x4 z = {0.f, 0.f, 0.f, 0.f};
            acc[i][j] = z;
        }

    // ---- PIN the W fragments: "+v" marks each as modified-in-place, so
    // the compiler cannot sink/rematerialize the loads past this point
    // (rule #17). The K-loop below is then provably free of global ops.
#pragma unroll
    for (int kk = 0; kk < 8; ++kk)
#pragma unroll
        for (int j = 0; j < 2; ++j)
            asm volatile("" : "+v"(wfr[j][kk]));
    __builtin_amdgcn_sched_barrier(0);

    __syncthreads();   // vmcnt(0) drain: stage AND W-hoist complete

    // ---- 3) K-loop: 8 steps of 32. PURE LDS + register MFMA -- no global
    // memory operations of any kind inside the loop.
#pragma unroll
    for (int kk = 0; kk < 8; ++kk) {
        short8 xfr[2];
        const int g0 = kk * 8 + quad * 2;   // global 16B-chunk index
#pragma unroll
        for (int i = 0; i < 2; ++i) {
            const int r = i * 16 + lrow;
            f32x4 f0 = *(const f32x4*)&As[r * 256 + (((g0    ) ^ (r & 7)) << 2)];
            f32x4 f1 = *(const f32x4*)&As[r * 256 + (((g0 + 1) ^ (r & 7)) << 2)];
            xfr[i] = pack8v(f0, f1);
        }
#pragma unroll
        for (int j = 0; j < 2; ++j)
#pragma unroll
            for (int i = 0; i < 2; ++i)
                acc[i][j] = __builtin_amdgcn_mfma_f32_16x16x32_bf16(
                    wfr[j][kk], xfr[i], acc[i][j], 0, 0, 0);
    }

    // ---- Bias (loaded here, post-K-loop, to keep pre-barrier VGPRs low).
    f32x4 bj[2];
    if (MODE == 0) {
        const float* bsum = (const float*)bp;
#pragma unroll
        for (int j = 0; j < 2; ++j)
            bj[j] = *(const f32x4*)(bsum + w8 * 32 + j * 16 + quad * 4);
    } else {
        const float* bias = (const float*)bp;
#pragma unroll
        for (int j = 0; j < 2; ++j) {
            const int d0 = w8 * 32 + j * 16 + quad * 4;
#pragma unroll
            for (int r = 0; r < 4; ++r) {
                float sum = 0.f;
#pragma unroll
                for (int i = 0; i < 5; ++i) sum += bias[i * H_ + d0 + r];
                bj[j][r] = sum;
            }
        }
    }

    // ---- Epilogue. A=W, B=x -> col(lane&15)=tile row, row(quad*4+reg)=d.
#pragma unroll
    for (int j = 0; j < 2; ++j) {
        const int d0 = w8 * 32 + j * 16 + quad * 4;
#pragma unroll
        for (int i = 0; i < 2; ++i) {
            const int rg = i * 16 + lrow;
            if (rg <= rmax) {
                f32x4 v = acc[i][j] + bj[j];
                *(f32x4*)(out + (xrow0 + rstride * rg) * H_ + d0) = v;
            }
        }
    }
}

extern "C" void kernel_launch(void* const* d_in, const int* in_sizes, int n_in,
                              void* d_out, int out_size, void* d_ws, size_t ws_size,
                              hipStream_t stream) {
    const float* x    = (const float*)d_in[0];
    const float* W    = (const float*)d_in[1];
    const float* bias = (const float*)d_in[2];
    float* out = (float*)d_out;

    const size_t w_elems  = (size_t)5 * H_ * H_;
    const size_t ws_need  = w_elems * sizeof(unsigned short) + H_ * sizeof(float);

    const int grid = 2048 + 12;
    if (ws_size >= ws_need) {
        unsigned short* Wbf = (unsigned short*)d_ws;
        float* bsum = (float*)((char*)d_ws + w_elems * sizeof(unsigned short));
        prep_kernel<<<dim3(160), dim3(256), 0, stream>>>(W, bias, Wbf, bsum);
        sel_gemm_kernel<0><<<dim3(grid), dim3(512), 0, stream>>>(
            x, (const void*)Wbf, (const void*)bsum, out);
    } else {
        sel_gemm_kernel<1><<<dim3(grid), dim3(512), 0, stream>>>(
            x, (const void*)W, (const void*)bias, out);
    }
}